// Round 1
// baseline (29.889 us; speedup 1.0000x reference)
//
#include <hip/hip_runtime.h>

// reference: out[b,l,c,t,f] = prototypes[labels[b,l], c, t, f]
// B=512, L=21, NCHAN=1, T=29, F=129  -> row = NCHAN*T*F = 3741 floats
// total out = 512*21*3741 = 40,223,232 floats (fits in int32)

#define ROW_ELEMS 3741
#define TOTAL_ELEMS (512u * 21u * 3741u)   // 40,223,232

__global__ __launch_bounds__(256) void gather_proto_kernel(
    const int* __restrict__ labels,       // (B*L) int32
    const float* __restrict__ protos,     // (25, 3741) float32
    float* __restrict__ out)              // (B*L, 3741) float32
{
    const unsigned nv = TOTAL_ELEMS / 4u;          // 10,055,808 vec4 chunks
    const unsigned stride = gridDim.x * blockDim.x;
    for (unsigned v = blockIdx.x * blockDim.x + threadIdx.x; v < nv; v += stride) {
        const unsigned base = v * 4u;
        const unsigned r0 = base / ROW_ELEMS;      // magic-multiply divide
        const unsigned e0 = base - r0 * ROW_ELEMS;
        if (e0 + 3u < ROW_ELEMS) {
            // whole chunk inside one row: scalar loads (cache hits), vec4 store
            const float* p = protos + (unsigned)labels[r0] * ROW_ELEMS + e0;
            float4 val;
            val.x = p[0];
            val.y = p[1];
            val.z = p[2];
            val.w = p[3];
            *reinterpret_cast<float4*>(out + base) = val;
        } else {
            // chunk straddles a row boundary (rare: ~1/935 chunks)
#pragma unroll
            for (unsigned k = 0; k < 4u; ++k) {
                const unsigned idx = base + k;
                const unsigned r = idx / ROW_ELEMS;
                const unsigned e = idx - r * ROW_ELEMS;
                out[idx] = protos[(unsigned)labels[r] * ROW_ELEMS + e];
            }
        }
    }
}

extern "C" void kernel_launch(void* const* d_in, const int* in_sizes, int n_in,
                              void* d_out, int out_size, void* d_ws, size_t ws_size,
                              hipStream_t stream) {
    // setup_inputs() order: inputs (unused), labels, prototypes
    const int*   labels = (const int*)d_in[1];
    const float* protos = (const float*)d_in[2];
    float*       out    = (float*)d_out;

    const unsigned nv = TOTAL_ELEMS / 4u;
    unsigned blocks = (nv + 255u) / 256u;
    if (blocks > 2048u) blocks = 2048u;   // grid-stride the rest (G11)
    gather_proto_kernel<<<blocks, 256, 0, stream>>>(labels, protos, out);
}